// Round 3
// baseline (925.708 us; speedup 1.0000x reference)
//
#include <hip/hip_runtime.h>

typedef unsigned short u16;
typedef unsigned int   u32;
typedef unsigned long long u64;
typedef __attribute__((ext_vector_type(4))) float floatx4;
typedef __attribute__((ext_vector_type(8))) short shortx8;
typedef __attribute__((ext_vector_type(8))) u16   ushortx8;
typedef __attribute__((ext_vector_type(4))) u32   uintx4;

#define B_   2
#define S_   2048
#define DIM_ 4096
#define NH_  32
#define NKV_ 8
#define HD_  128
#define MTOT (B_*S_)            // 4096 rows
#define NQKV (NH_*HD_ + 2*NKV_*HD_)  // 6144
// Q pre-scale: 1/sqrt(128) * log2(e)  -> scores in log2 domain, softmax uses exp2
#define QSCALE 0.12753785735803168f
#define KSCALE 1.0f

typedef __attribute__((address_space(3))) u32 lds_u32;
typedef const __attribute__((address_space(1))) u32 gbl_u32;

__device__ inline u16 f2bf(float f) {                 // native RNE cvt
  __bf16 h = (__bf16)f;
  return __builtin_bit_cast(u16, h);
}
__device__ inline float bf2f(u16 u) {
  u32 x = ((u32)u) << 16;
  return __builtin_bit_cast(float, x);
}
__device__ inline shortx8 ldfrag(const u16* p) {
  return __builtin_bit_cast(shortx8, *(const uint4*)p);
}

// ---------------- fp32 -> bf16 cast (x) ----------------
__global__ __launch_bounds__(256) void cvt_f32_bf16(const float* __restrict__ src,
                                                    u16* __restrict__ dst) {
  int i = blockIdx.x * 256 + threadIdx.x;          // 8 elems / thread
  const float4* s4 = (const float4*)src;
  float4 a = s4[2*i], c = s4[2*i+1];
  ushortx8 o;
  o[0]=f2bf(a.x); o[1]=f2bf(a.y); o[2]=f2bf(a.z); o[3]=f2bf(a.w);
  o[4]=f2bf(c.x); o[5]=f2bf(c.y); o[6]=f2bf(c.z); o[7]=f2bf(c.w);
  *(ushortx8*)(dst + (size_t)i*8) = o;
}

// ---------------- weight transpose + cast: w (K,N) fp32 -> wt (N,K) bf16 ----------------
__global__ __launch_bounds__(256) void transpose_cvt(const float* __restrict__ w,
                                                     u16* __restrict__ wt, int K, int N) {
  __shared__ float tile[32][33];
  int n0 = blockIdx.x * 32, k0 = blockIdx.y * 32;
  int tx = threadIdx.x & 31, ty = threadIdx.x >> 5;
#pragma unroll
  for (int i = 0; i < 4; i++) {
    int r = ty*4 + i;
    tile[r][tx] = w[(size_t)(k0 + r)*N + n0 + tx];
  }
  __syncthreads();
#pragma unroll
  for (int i = 0; i < 4; i++) {
    int n = ty*4 + i;
    wt[(size_t)(n0 + n)*K + k0 + tx] = f2bf(tile[tx][n]);
  }
}

// ---------------- GEMM: C(M,N) = A(M,K) @ Bt(N,K)^T, bf16 in, fp32 acc ----------------
// m97 structure + XOR-swizzled LDS: 128x128 tile, BK=64, global_load_lds width-16.
template<int OUT_BF16>
__global__ __launch_bounds__(256) void gemm_bt(const u16* __restrict__ A,
                                               const u16* __restrict__ Bt,
                                               void* __restrict__ Cv,
                                               int M, int N, int K) {
  __shared__ u16 As[128*64];
  __shared__ u16 Bs[128*64];
  const int tid = threadIdx.x;
  const int w = tid >> 6, l = tid & 63, quad = l >> 4, c16 = l & 15;
  const int bm = blockIdx.y * 128, bn = blockIdx.x * 128;
  const int wm = (w & 1) * 64, wn = (w >> 1) * 64;
  const int drow = l >> 3;                  // 0..7  (8 rows per 1KB DMA instr)
  const int gchunk = (l & 7) ^ drow;        // swizzled global chunk this lane fetches
  const int dcol = gchunk * 8;              // u16 col offset
  floatx4 acc[4][4];
#pragma unroll
  for (int mi = 0; mi < 4; mi++)
#pragma unroll
    for (int ni = 0; ni < 4; ni++) acc[mi][ni] = floatx4{0.f,0.f,0.f,0.f};

  for (int k0 = 0; k0 < K; k0 += 64) {
    __syncthreads();
#pragma unroll
    for (int j = 0; j < 4; j++) {
      int row = w*32 + j*8 + drow;          // rowbase&7 == 0, so row&7 == drow
      __builtin_amdgcn_global_load_lds(
          (gbl_u32*)(A + (size_t)(bm + row)*K + k0 + dcol),
          (lds_u32*)(As + (w*32 + j*8)*64), 16, 0, 0);
      __builtin_amdgcn_global_load_lds(
          (gbl_u32*)(Bt + (size_t)(bn + row)*K + k0 + dcol),
          (lds_u32*)(Bs + (w*32 + j*8)*64), 16, 0, 0);
    }
    __syncthreads();
#pragma unroll
    for (int ks = 0; ks < 2; ks++) {
      shortx8 af[4], bfr[4];
#pragma unroll
      for (int mi = 0; mi < 4; mi++) {
        int row = wm + mi*16 + c16;
        int ch  = (ks*4 + quad) ^ (row & 7);
        af[mi] = ldfrag(As + row*64 + ch*8);
      }
#pragma unroll
      for (int ni = 0; ni < 4; ni++) {
        int row = wn + ni*16 + c16;
        int ch  = (ks*4 + quad) ^ (row & 7);
        bfr[ni] = ldfrag(Bs + row*64 + ch*8);
      }
#pragma unroll
      for (int mi = 0; mi < 4; mi++)
#pragma unroll
        for (int ni = 0; ni < 4; ni++)
          acc[mi][ni] = __builtin_amdgcn_mfma_f32_16x16x32_bf16(af[mi], bfr[ni], acc[mi][ni], 0, 0, 0);
    }
  }
  // epilogue: C/D layout col=lane&15, row=quad*4+reg
#pragma unroll
  for (int mi = 0; mi < 4; mi++)
#pragma unroll
    for (int i = 0; i < 4; i++) {
      int row = bm + wm + mi*16 + quad*4 + i;
#pragma unroll
      for (int ni = 0; ni < 4; ni++) {
        int col = bn + wn + ni*16 + c16;
        float v = acc[mi][ni][i];
        if (OUT_BF16) ((u16*)Cv)[(size_t)row*N + col] = f2bf(v);
        else          ((float*)Cv)[(size_t)row*N + col] = v;
      }
    }
}

// ---------------- RoPE on q,k parts of qkv_pre; Q pre-scaled by log2e/sqrt(HD) ----------------
__global__ __launch_bounds__(256) void rope_kernel(const u16* __restrict__ qkv,
                                                   const float* __restrict__ fc,
                                                   const float* __restrict__ fs,
                                                   u16* __restrict__ q_r,
                                                   u16* __restrict__ k_r) {
  u32 idx  = blockIdx.x * 256 + threadIdx.x;     // MTOT*40*64 pairs
  u32 t    = idx & 63;
  u32 rest = idx >> 6;
  u32 m    = rest / 40u;
  u32 hh   = rest - m*40u;
  u32 s    = m & (S_ - 1);
  float c  = fc[s*64 + t], sn = fs[s*64 + t];
  u32 src; u16* dst; u32 dstoff; float scale;
  if (hh < (u32)NH_) {
    src = m*NQKV + hh*HD_ + 2*t;  dst = q_r;  dstoff = m*(NH_*HD_) + hh*HD_ + 2*t;  scale = QSCALE;
  } else {
    u32 hk = hh - NH_;
    src = m*NQKV + NH_*HD_ + hk*HD_ + 2*t;  dst = k_r;  dstoff = m*(NKV_*HD_) + hk*HD_ + 2*t;  scale = KSCALE;
  }
  u32 pair = *(const u32*)(qkv + src);
  float xr = bf2f((u16)(pair & 0xffffu));
  float xi = bf2f((u16)(pair >> 16));
  float orr = (xr*c - xi*sn) * scale;
  float oii = (xr*sn + xi*c) * scale;
  u32 outp = (u32)f2bf(orr) | ((u32)f2bf(oii) << 16);
  *(u32*)(dst + dstoff) = outp;
}

// ---------------- V transpose: qkv_pre v-part (m, hk, d) -> vt (b, hk, d, s) ----------------
__global__ __launch_bounds__(256) void v_transpose(const u16* __restrict__ qkv,
                                                   u16* __restrict__ vt) {
  __shared__ u16 tile[32][33];
  int bh = blockIdx.y; int b = bh >> 3, hk = bh & 7;
  int ts = (blockIdx.x & 63) * 32;   // s tile
  int td = (blockIdx.x >> 6) * 32;   // d tile
  int tx = threadIdx.x & 31, ty = threadIdx.x >> 5;
#pragma unroll
  for (int i = 0; i < 4; i++) {
    int r = ty*4 + i;
    tile[r][tx] = qkv[(size_t)(b*S_ + ts + r)*NQKV + (NH_*HD_ + NKV_*HD_) + hk*HD_ + td + tx];
  }
  __syncthreads();
#pragma unroll
  for (int i = 0; i < 4; i++) {
    int d = ty*4 + i;
    vt[((size_t)bh*HD_ + td + d)*S_ + ts + tx] = tile[tx][d];
  }
}

// ---------------- Flash attention: swapped-operand (T12 structure), 64-q tile / block ----------------
// Round-3: counters showed LDS-pipe + serialization bound (BANK_CONFLICT 1.9e7 constant
// across layouts => P-scatter writes; P write->lgkmcnt(0)->read chain serializes every tile).
//  (a) S^T = mfma(K,Q): each lane owns ONE q-row (col c16); 64 k spread 16-per-quad.
//      Softmax is lane-scalar: 15 fmax + 2 shfl_xor; m/lsum/alpha per-lane scalars.
//  (b) P stays in registers: O^T = mfma(V^T, P). P B-frag built by bf16-pair packing +
//      two conditional-exchange stages (shfl_xor 32 then 16) that swap lane bits {5,4}
//      with the kb register-index bit.  No P LDS write/read, no lgkm serialization.
//  (c) Q fragments loaded direct from global (contiguous 16B); Qs LDS dropped (80->64KB).
//  (d) K/V double-buffer DMA prefetch kept from round 2; defer-max (THR=8) kept.
__global__ __launch_bounds__(256) void attn_kernel(const u16* __restrict__ Q,
                                                   const u16* __restrict__ Kr,
                                                   const u16* __restrict__ Vt,
                                                   u16* __restrict__ Out) {
  __shared__ u16 Ks[2][64*128];      // swizzled K tiles, double-buffered
  __shared__ u16 Vts[2][128*64];     // swizzled V^T tiles, double-buffered
  const int tid = threadIdx.x;
  const int w = tid >> 6, l = tid & 63, quad = l >> 4, c16 = l & 15;
  const int qt = blockIdx.x, h = blockIdx.y, b = blockIdx.z;
  const int hk = h >> 2;                 // GQA: 4 query heads per kv head

  const u16* kbase = Kr + (size_t)(b*S_)*(NKV_*HD_) + hk*HD_;
  const u16* vbase = Vt + (size_t)(b*NKV_ + hk)*HD_*S_;

  // ---- Q fragments direct from global: lane owns q-row w*16+c16, d = kk*32+quad*8..+7 ----
  shortx8 aq[4];
  {
    const u16* qrow = Q + (size_t)(b*S_ + qt*64 + w*16 + c16)*(NH_*HD_) + h*HD_;
#pragma unroll
    for (int kk = 0; kk < 4; kk++)
      aq[kk] = ldfrag(qrow + kk*32 + quad*8);
  }

  // ---- stage K/V tile 0 into buffer 0 ----
#pragma unroll
  for (int j = 0; j < 4; j++) {
    int rowb = w*16 + j*4;
    int r = rowb + (l >> 4);
    int gch = (l & 15) ^ (r & 7);
    __builtin_amdgcn_global_load_lds(
        (gbl_u32*)(kbase + (size_t)r*(NKV_*HD_) + gch*8),
        (lds_u32*)(Ks[0] + rowb*128), 16, 0, 0);
    int rowbv = w*32 + j*8;
    int rv = rowbv + (l >> 3);
    int gchv = (l & 7) ^ (rv & 7);
    __builtin_amdgcn_global_load_lds(
        (gbl_u32*)(vbase + (size_t)rv*S_ + gchv*8),
        (lds_u32*)(Vts[0] + rowbv*64), 16, 0, 0);
  }
  __syncthreads();                     // drains tile-0 DMA

  floatx4 o[8];                        // O^T: lane col = q, rows d = f*16 + quad*4 + i
#pragma unroll
  for (int f = 0; f < 8; f++) o[f] = floatx4{0.f,0.f,0.f,0.f};
  float m = -1e30f, lsum = 0.f;        // per-lane (per-q-row) scalars

  int cur = 0;
  for (int kt = 0; kt < S_/64; kt++) {
    if (kt) __syncthreads();     // drains buf[cur] DMA + prev reads of buf[cur^1]

    // prefetch tile kt+1 into buf[cur^1]; latency hides under this tile's compute
    if (kt + 1 < S_/64) {
      int nb = cur ^ 1;
#pragma unroll
      for (int j = 0; j < 4; j++) {
        int rowb = w*16 + j*4;
        int r = rowb + (l >> 4);
        int gch = (l & 15) ^ (r & 7);
        __builtin_amdgcn_global_load_lds(
            (gbl_u32*)(kbase + (size_t)((kt+1)*64 + r)*(NKV_*HD_) + gch*8),
            (lds_u32*)(Ks[nb] + rowb*128), 16, 0, 0);
        int rowbv = w*32 + j*8;
        int rv = rowbv + (l >> 3);
        int gchv = (l & 7) ^ (rv & 7);
        __builtin_amdgcn_global_load_lds(
            (gbl_u32*)(vbase + (size_t)rv*S_ + (kt+1)*64 + gchv*8),
            (lds_u32*)(Vts[nb] + rowbv*64), 16, 0, 0);
      }
    }

    // S^T = mfma(K, Q): sc[kb] C-layout: col c16 = q, row quad*4+i -> k = kb*16+quad*4+i
    floatx4 sc[4];
#pragma unroll
    for (int kb = 0; kb < 4; kb++) sc[kb] = floatx4{0.f,0.f,0.f,0.f};
    __builtin_amdgcn_s_setprio(1);
#pragma unroll
    for (int kk = 0; kk < 4; kk++)
#pragma unroll
      for (int kb = 0; kb < 4; kb++) {
        int rowk = kb*16 + c16;
        shortx8 kf = ldfrag(Ks[cur] + rowk*128 + ((kk*4 + quad) ^ (c16 & 7))*8);
        sc[kb] = __builtin_amdgcn_mfma_f32_16x16x32_bf16(kf, aq[kk], sc[kb], 0, 0, 0);
      }
    __builtin_amdgcn_s_setprio(0);

    // lane-scalar online softmax for this lane's q-row
    float mx = fmaxf(fmaxf(fmaxf(sc[0][0], sc[0][1]), fmaxf(sc[0][2], sc[0][3])),
                     fmaxf(fmaxf(sc[1][0], sc[1][1]), fmaxf(sc[1][2], sc[1][3])));
    mx = fmaxf(mx, fmaxf(fmaxf(fmaxf(sc[2][0], sc[2][1]), fmaxf(sc[2][2], sc[2][3])),
                         fmaxf(fmaxf(sc[3][0], sc[3][1]), fmaxf(sc[3][2], sc[3][3]))));
    mx = fmaxf(mx, __shfl_xor(mx, 16));
    mx = fmaxf(mx, __shfl_xor(mx, 32));

    float rs = 0.f;
    if (__all(mx - m <= 8.0f)) {
      // defer: keep old max, P bounded by 2^8, no rescale
#pragma unroll
      for (int kb = 0; kb < 4; kb++)
#pragma unroll
        for (int i = 0; i < 4; i++) {
          float p = __builtin_amdgcn_exp2f(sc[kb][i] - m);
          sc[kb][i] = p; rs += p;
        }
    } else {
      float mn = fmaxf(m, mx);
      float al = __builtin_amdgcn_exp2f(m - mn);
      m = mn;
#pragma unroll
      for (int kb = 0; kb < 4; kb++)
#pragma unroll
        for (int i = 0; i < 4; i++) {
          float p = __builtin_amdgcn_exp2f(sc[kb][i] - mn);
          sc[kb][i] = p; rs += p;
        }
      lsum *= al;
#pragma unroll
      for (int f = 0; f < 8; f++) o[f] *= al;
    }
    rs += __shfl_xor(rs, 16);
    rs += __shfl_xor(rs, 32);
    lsum += rs;

    // pack P to bf16 pairs: pk[kb][j] holds k = kb*16 + quad*4 + {2j, 2j+1}
    u32 pk[4][2];
#pragma unroll
    for (int kb = 0; kb < 4; kb++)
#pragma unroll
      for (int j = 0; j < 2; j++)
        pk[kb][j] = (u32)f2bf(sc[kb][2*j]) | ((u32)f2bf(sc[kb][2*j+1]) << 16);

    // stage 1: swap lane bit5 (xor 32) with kb low bit
#pragma unroll
    for (int kh = 0; kh < 2; kh++)
#pragma unroll
      for (int j = 0; j < 2; j++) {
        u32 tr = (quad >= 2) ? pk[kh*2][j] : pk[kh*2+1][j];
        tr = (u32)__shfl_xor((int)tr, 32);
        if (quad >= 2) pk[kh*2][j] = tr; else pk[kh*2+1][j] = tr;
      }
    // stage 2: swap lane bit4 (xor 16) with the same slot bit
#pragma unroll
    for (int kh = 0; kh < 2; kh++)
#pragma unroll
      for (int j = 0; j < 2; j++) {
        u32 tr = (quad & 1) ? pk[kh*2][j] : pk[kh*2+1][j];
        tr = (u32)__shfl_xor((int)tr, 16);
        if (quad & 1) pk[kh*2][j] = tr; else pk[kh*2+1][j] = tr;
      }
    // now pk[2*kk2 + s][j] = P[q_lane][k = kk2*32 + quad*8 + 4s + 2j + {0,1}]

    // O^T += V^T P^T : A = V^T frag (row d), B = P frag (col q)
    __builtin_amdgcn_s_setprio(1);
#pragma unroll
    for (int kk2 = 0; kk2 < 2; kk2++) {
      shortx8 pf = __builtin_bit_cast(shortx8,
          uintx4{pk[2*kk2][0], pk[2*kk2][1], pk[2*kk2+1][0], pk[2*kk2+1][1]});
#pragma unroll
      for (int f = 0; f < 8; f++) {
        int rv = f*16 + c16;
        shortx8 vf = ldfrag(Vts[cur] + rv*64 + ((kk2*4 + quad) ^ (rv & 7))*8);
        o[f] = __builtin_amdgcn_mfma_f32_16x16x32_bf16(vf, pf, o[f], 0, 0, 0);
      }
    }
    __builtin_amdgcn_s_setprio(0);
    cur ^= 1;
  }

  // normalize + store: lane's q-row = qt*64+w*16+c16; d = f*16 + quad*4 + i (4 consecutive)
  {
    float inv = 1.f / lsum;
    size_t base = (size_t)(b*S_ + qt*64 + w*16 + c16)*(NH_*HD_) + h*HD_ + quad*4;
#pragma unroll
    for (int f = 0; f < 8; f++) {
      u64 pkd = (u64)f2bf(o[f][0]*inv)
              | ((u64)f2bf(o[f][1]*inv) << 16)
              | ((u64)f2bf(o[f][2]*inv) << 32)
              | ((u64)f2bf(o[f][3]*inv) << 48);
      *(u64*)(Out + base + f*16) = pkd;
    }
  }
}

extern "C" void kernel_launch(void* const* d_in, const int* in_sizes, int n_in,
                              void* d_out, int out_size, void* d_ws, size_t ws_size,
                              hipStream_t stream) {
  (void)in_sizes; (void)n_in; (void)out_size; (void)ws_size;
  const float* x  = (const float*)d_in[0];
  // d_in[1] = start_pos (unused; reference ignores it)
  const float* fc = (const float*)d_in[2];
  const float* fs = (const float*)d_in[3];
  const float* wq = (const float*)d_in[4];
  const float* wk = (const float*)d_in[5];
  const float* wv = (const float*)d_in[6];
  const float* wo = (const float*)d_in[7];
  float* out = (float*)d_out;

  // workspace layout (160 MB total), with lifetime-based reuse:
  char* ws = (char*)d_ws;
  u16* xb    = (u16*)(ws);                    // x bf16 (33.5MB); reused as attn_out after QKV
  u16* wallt = (u16*)(ws + 33554432ull);      // [wq|wk|wv]^T bf16, 6144x4096 (50.3MB)
  u16* q_r   = (u16*)(ws + 33554432ull);      // overlays wallt after QKV GEMM (33.5MB)
  u16* k_r   = (u16*)(ws + 67108864ull);      // (8.4MB)
  u16* vt    = (u16*)(ws + 75497472ull);      // (8.4MB)
  u16* wot   = (u16*)(ws + 83886080ull);      // wo^T bf16 (33.5MB)
  u16* qkvp  = (u16*)(ws + 117440512ull);     // qkv_pre bf16, 4096x6144 (50.3MB); end 160MB

  cvt_f32_bf16<<<8192, 256, 0, stream>>>(x, xb);
  transpose_cvt<<<dim3(128,128), 256, 0, stream>>>(wq, wallt, 4096, 4096);
  transpose_cvt<<<dim3(32,128),  256, 0, stream>>>(wk, wallt + (size_t)4096*4096, 4096, 1024);
  transpose_cvt<<<dim3(32,128),  256, 0, stream>>>(wv, wallt + (size_t)5120*4096, 4096, 1024);
  transpose_cvt<<<dim3(128,128), 256, 0, stream>>>(wo, wot, 4096, 4096);

  gemm_bt<1><<<dim3(48,32), 256, 0, stream>>>(xb, wallt, qkvp, MTOT, NQKV, DIM_);

  rope_kernel<<<40960, 256, 0, stream>>>(qkvp, fc, fs, q_r, k_r);
  v_transpose<<<dim3(256,16), 256, 0, stream>>>(qkvp, vt);

  attn_kernel<<<dim3(32,32,2), 256, 0, stream>>>(q_r, k_r, vt, xb);

  gemm_bt<0><<<dim3(32,32), 256, 0, stream>>>(xb, wot, out, MTOT, DIM_, 4096);
}